// Round 1
// 2733.177 us; speedup vs baseline: 1.0242x; 1.0242x over previous
//
#include <hip/hip_runtime.h>

// ---------------------------------------------------------------------------
// SpatioTemporalTransformerXL forward on gfx950.
//  - residual stream h stays fp32 in d_out, updated in place
//  - LN kernels emit bf16 x; all GEMMs are bf16 MFMA (16x16x32), fp32 acc
//  - GEMM: 256x256 tile, 8 waves (2Mx4N), BK=32, ring-4 LDS (128KB),
//    3-tile-deep global_load_lds prefetch with COUNTED vmcnt (T3+T4),
//    raw s_barrier (no vmcnt drain), setprio around MFMA cluster (T5),
//    XOR granule swizzle (conflict-free ds_read_b128), XCD-aware block swizzle
// ---------------------------------------------------------------------------

#define AS1 __attribute__((address_space(1)))
#define AS3 __attribute__((address_space(3)))

using bf16x8 = __attribute__((ext_vector_type(8))) short;   // 8 bf16 = 4 VGPRs
using f32x4  = __attribute__((ext_vector_type(4))) float;

__device__ __forceinline__ f32x4 mfma_bf16(bf16x8 a, bf16x8 b, f32x4 c) {
  return __builtin_amdgcn_mfma_f32_16x16x32_bf16(a, b, c, 0, 0, 0);
}

__device__ __forceinline__ void async16(const void* g, void* l) {
  __builtin_amdgcn_global_load_lds((const AS1 void*)g, (AS3 void*)l, 16, 0, 0);
}

// fp32 -> bf16 RNE
__device__ __forceinline__ short f2bs(float f) {
  union { float f; unsigned u; } x; x.f = f;
  unsigned r = x.u + 0x7fffu + ((x.u >> 16) & 1u);
  return (short)(r >> 16);
}

__device__ __forceinline__ f32x4 fzero() {
  f32x4 v; v[0] = 0.f; v[1] = 0.f; v[2] = 0.f; v[3] = 0.f; return v;
}

__device__ __forceinline__ float quad16_max(float v) {
  v = fmaxf(v, __shfl_xor(v, 1));
  v = fmaxf(v, __shfl_xor(v, 2));
  v = fmaxf(v, __shfl_xor(v, 4));
  v = fmaxf(v, __shfl_xor(v, 8));
  return v;
}
__device__ __forceinline__ float quad16_sum(float v) {
  v += __shfl_xor(v, 1); v += __shfl_xor(v, 2);
  v += __shfl_xor(v, 4); v += __shfl_xor(v, 8);
  return v;
}

// ---------------------------------------------------------------------------
// GEMM: C[M,N] = A[M,K](bf16) * BT[N,K]^T(bf16)  + epilogue
// MODE 0: outB = bf16(acc)                       (QKV projections)
// MODE 1: outF = acc + bias[col] + resid         (output proj / FFN2, fp32)
// MODE 2: outB = bf16(gelu_tanh(acc + bias))     (FFN1)
//
// Tile 256x256, BK=32. LDS ring of 4 slots; slot = 32KB = A[256][32] + B[256][32]
// rows of 64B = 4 granules of 16B; granule g of row r stored at g ^ ((r>>1)&3)
// -> ds_read_b128 per 16-lane group hits each bank-group exactly twice (free).
// global_load_lds inverts the swizzle in the global k-offset (dest stays linear).
//
// Pipeline (per wave, per K-tile t):
//   stage(t+3) -> slot (t+3)&3 = (t-1)&3   [its readers finished before the
//                                           barrier at the end of iter t-1]
//   s_waitcnt vmcnt(12)   [tiles t+1..t+3 may be in flight; tile t has landed]
//   s_barrier; ds_read 12x b128 from slot t&3; lgkmcnt(0); s_barrier
//   setprio(1); 32x MFMA; setprio(0)
// Never vmcnt(0) in steady state; tail ladder 8/4/0.
// ---------------------------------------------------------------------------
template<int MODE>
__global__ __launch_bounds__(512, 2) void gemm256(
    const short* __restrict__ A, const short* __restrict__ BT,
    const float* __restrict__ bias, const float* __restrict__ resid,
    float* __restrict__ outF, short* __restrict__ outB,
    int M, int N, int K, int nx)
{
  __shared__ __align__(16) short lds[65536];   // 128KB: 4 slots x (A 16KB + B 16KB)
  (void)M;
  const int tid  = threadIdx.x;
  const int wave = tid >> 6, lane = tid & 63;
  const int quad = lane >> 4, l16 = lane & 15;
  const int wm = wave >> 2, wn = wave & 3;     // 2 x 4 wave grid, 128x64 each

  // XCD-aware swizzle: 8 consecutive blocks (one per XCD) share a B column-panel;
  // per XCD, nx consecutive blocks share one A row-panel (L2-resident).
  const unsigned flat = blockIdx.x;
  const unsigned su = flat >> 3;
  const unsigned nxu = (unsigned)nx;
  const long bm0 = (long)((flat & 7u) + 8u * (su / nxu)) * 256;
  const long bn0 = (long)(su % nxu) * 256;

  // ---- staging geometry: chunk = 16 rows x 32 shorts (1KB per wave-instr) ----
  const int srow = lane >> 2;                              // row within chunk
  const int skof = ((lane & 3) ^ ((lane >> 3) & 3)) * 8;   // swizzle-inverted k-off
  const int r0 = wave * 32;                                // this wave's rows
  const short* gA0 = A  + (bm0 + r0 + srow) * (long)K + skof;
  const short* gA1 = gA0 + 16 * (long)K;
  const short* gB0 = BT + (bn0 + r0 + srow) * (long)K + skof;
  const short* gB1 = gB0 + 16 * (long)K;
  char* const lbase = (char*)lds;
  const int dA0 = r0 * 64, dA1 = (r0 + 16) * 64;           // byte offsets in slot
  const int dB0 = 16384 + r0 * 64, dB1 = 16384 + (r0 + 16) * 64;

  // ---- fragment ds_read offsets (shorts), swizzled ----
  int aoff[8], boff[4];
#pragma unroll
  for (int i = 0; i < 8; ++i) {
    int row = wm * 128 + i * 16 + l16;
    aoff[i] = row * 32 + (quad ^ ((row >> 1) & 3)) * 8;
  }
#pragma unroll
  for (int j = 0; j < 4; ++j) {
    int row = wn * 64 + j * 16 + l16;
    boff[j] = 8192 + row * 32 + (quad ^ ((row >> 1) & 3)) * 8;
  }

  f32x4 acc[8][4];
#pragma unroll
  for (int i = 0; i < 8; ++i)
#pragma unroll
    for (int j = 0; j < 4; ++j) acc[i][j] = fzero();

  const int nt = K >> 5;                                   // K/32; K in {768,3072}

#define STAGE(t)                                                         \
  do {                                                                   \
    const int sb_ = ((t) & 3) * 32768;                                   \
    const long ko_ = (long)(t) * 32;                                     \
    async16(gA0 + ko_, lbase + sb_ + dA0);                               \
    async16(gA1 + ko_, lbase + sb_ + dA1);                               \
    async16(gB0 + ko_, lbase + sb_ + dB0);                               \
    async16(gB1 + ko_, lbase + sb_ + dB1);                               \
  } while (0)

  // prologue: 3 tiles in flight (12 loads/wave)
  STAGE(0); STAGE(1); STAGE(2);

  for (int t = 0; t < nt; ++t) {
    if (t + 3 < nt) STAGE(t + 3);            // overwrites slot (t-1)&3: safe
    const int ahead = nt - 1 - t;            // counted vmcnt: never 0 mid-loop
    if (ahead >= 3)      asm volatile("s_waitcnt vmcnt(12)" ::: "memory");
    else if (ahead == 2) asm volatile("s_waitcnt vmcnt(8)"  ::: "memory");
    else if (ahead == 1) asm volatile("s_waitcnt vmcnt(4)"  ::: "memory");
    else                 asm volatile("s_waitcnt vmcnt(0)"  ::: "memory");
    __builtin_amdgcn_s_barrier();            // all waves see tile t landed
    asm volatile("" ::: "memory");
    __builtin_amdgcn_sched_barrier(0);       // keep ds_reads below the barrier

    const short* sbase = lds + (t & 3) * 16384;
    bf16x8 a[8], b[4];
#pragma unroll
    for (int i = 0; i < 8; ++i) a[i] = *(const bf16x8*)(sbase + aoff[i]);
#pragma unroll
    for (int j = 0; j < 4; ++j) b[j] = *(const bf16x8*)(sbase + boff[j]);
    asm volatile("s_waitcnt lgkmcnt(0)" ::: "memory");   // reads done before...
    __builtin_amdgcn_sched_barrier(0);
    __builtin_amdgcn_s_barrier();            // ...slot t&3 becomes writable

    __builtin_amdgcn_s_setprio(1);
#pragma unroll
    for (int i = 0; i < 8; ++i)
#pragma unroll
      for (int j = 0; j < 4; ++j)
        acc[i][j] = mfma_bf16(a[i], b[j], acc[i][j]);
    __builtin_amdgcn_s_setprio(0);
  }
#undef STAGE

  // ---- epilogue (C/D layout: col=l16, row=quad*4+r) ----
  const long rowbase = bm0 + wm * 128 + quad * 4;
  const long colbase = bn0 + wn * 64 + l16;
#pragma unroll
  for (int i = 0; i < 8; ++i)
#pragma unroll
    for (int j = 0; j < 4; ++j) {
      const long gc = colbase + j * 16;
#pragma unroll
      for (int r = 0; r < 4; ++r) {
        const long gr = rowbase + i * 16 + r;
        const size_t idx = (size_t)gr * N + gc;
        float v = acc[i][j][r];
        if (MODE == 0) {
          outB[idx] = f2bs(v);
        } else if (MODE == 1) {
          outF[idx] = v + bias[gc] + resid[idx];
        } else {
          float tt = v + bias[gc];
          float g = 0.5f * tt * (1.f + tanhf(0.7978845608f * (tt + 0.044715f * tt * tt * tt)));
          outB[idx] = f2bs(g);
        }
      }
    }
}

// ---------------------------------------------------------------------------
// LayerNorm: h fp32 [16384,768] -> bf16 x, one block per row, 256 threads.
// ---------------------------------------------------------------------------
__global__ __launch_bounds__(256) void ln_kernel(
    const float* __restrict__ h, const float* __restrict__ sc,
    const float* __restrict__ bi, short* __restrict__ out)
{
  const int row = blockIdx.x, tid = threadIdx.x;
  const float* hr = h + (long)row * 768;
  float x0 = hr[tid], x1 = hr[tid + 256], x2 = hr[tid + 512];
  __shared__ float red[4];
  float s = x0 + x1 + x2;
#pragma unroll
  for (int m = 32; m >= 1; m >>= 1) s += __shfl_xor(s, m);
  if ((tid & 63) == 0) red[tid >> 6] = s;
  __syncthreads();
  float mean = (red[0] + red[1] + red[2] + red[3]) * (1.f / 768.f);
  float d0 = x0 - mean, d1 = x1 - mean, d2 = x2 - mean;
  float q = d0 * d0 + d1 * d1 + d2 * d2;
#pragma unroll
  for (int m = 32; m >= 1; m >>= 1) q += __shfl_xor(q, m);
  __syncthreads();
  if ((tid & 63) == 0) red[tid >> 6] = q;
  __syncthreads();
  float var = (red[0] + red[1] + red[2] + red[3]) * (1.f / 768.f);
  float inv = rsqrtf(var + 1e-5f);
  long o = (long)row * 768;
  out[o + tid]       = f2bs(d0 * inv * sc[tid]       + bi[tid]);
  out[o + tid + 256] = f2bs(d1 * inv * sc[tid + 256] + bi[tid + 256]);
  out[o + tid + 512] = f2bs(d2 * inv * sc[tid + 512] + bi[tid + 512]);
}

// ---------------------------------------------------------------------------
// Weight transpose + bf16 cast: in fp32 [Kd][Nd] -> out bf16 [Nd][Kd]
// z = layer index (batched over gridDim.z)
// ---------------------------------------------------------------------------
__global__ __launch_bounds__(256) void transpose_w(
    const float* __restrict__ in, short* __restrict__ out, int Kd, int Nd,
    long inStride, long outStride)
{
  __shared__ float t[32][33];
  const int z = blockIdx.z;
  in  += (long)z * inStride;
  out += (long)z * outStride;
  const int n0 = blockIdx.x * 32, k0 = blockIdx.y * 32;
  const int r = threadIdx.x >> 5, c = threadIdx.x & 31;
#pragma unroll
  for (int rr = 0; rr < 4; ++rr)
    t[r + rr * 8][c] = in[(long)(k0 + r + rr * 8) * Nd + n0 + c];
  __syncthreads();
#pragma unroll
  for (int rr = 0; rr < 4; ++rr)
    out[(long)(n0 + r + rr * 8) * Kd + k0 + c] = f2bs(t[c][r + rr * 8]);
}

// ---------------------------------------------------------------------------
// Space attention: softmax over L=256. Grid (qtile=4, head=12, b*t=64),
// 256 threads = 4 waves; each wave owns 16 q-rows. qkv row stride 2304:
// cols [0,768) Q, [768,1536) K, [1536,2304) V, packed h*64+d.
// ---------------------------------------------------------------------------
__global__ __launch_bounds__(256) void attn_space(
    const short* __restrict__ qkv, short* __restrict__ ao)
{
  __shared__ __align__(16) short VT[64 * 256];      // VT[d][l]
  __shared__ __align__(16) short P[4][16 * 256];    // per-wave P[q][l]
  const int qt = blockIdx.x, hh = blockIdx.y, bt = blockIdx.z;
  const long tok0 = (long)bt * 256;
  const int tid = threadIdx.x, wave = tid >> 6, lane = tid & 63;
  const int quad = lane >> 4, l16 = lane & 15;

  // stage V^T
#pragma unroll
  for (int it = 0; it < 8; ++it) {
    int chunk = it * 256 + tid;
    int vl = chunk >> 3, d8 = (chunk & 7) * 8;
    bf16x8 v = *(const bf16x8*)(qkv + (tok0 + vl) * 2304 + 1536 + hh * 64 + d8);
#pragma unroll
    for (int e = 0; e < 8; ++e) VT[(d8 + e) * 256 + vl] = v[e];
  }

  const int qr = qt * 64 + wave * 16;
  bf16x8 qf[2];
#pragma unroll
  for (int kk = 0; kk < 2; ++kk)
    qf[kk] = *(const bf16x8*)(qkv + (tok0 + qr + l16) * 2304 + hh * 64 + kk * 32 + quad * 8);

  f32x4 S[16];
#pragma unroll
  for (int j = 0; j < 16; ++j) S[j] = fzero();
#pragma unroll
  for (int j = 0; j < 16; ++j)
#pragma unroll
    for (int kk = 0; kk < 2; ++kk) {
      bf16x8 kf = *(const bf16x8*)(qkv + (tok0 + j * 16 + l16) * 2304 + 768 + hh * 64 + kk * 32 + quad * 8);
      S[j] = mfma_bf16(qf[kk], kf, S[j]);
    }

  // softmax rows quad*4+r  (C/D layout: col=l16, row=quad*4+reg)
#pragma unroll
  for (int r = 0; r < 4; ++r) {
    float m = -1e30f;
#pragma unroll
    for (int j = 0; j < 16; ++j) m = fmaxf(m, S[j][r]);
    m = quad16_max(m);
    float sum = 0.f;
#pragma unroll
    for (int j = 0; j < 16; ++j) {
      float e = __expf((S[j][r] - m) * 0.125f);
      S[j][r] = e; sum += e;
    }
    sum = quad16_sum(sum);
    float inv = 1.f / sum;
#pragma unroll
    for (int j = 0; j < 16; ++j)
      P[wave][(quad * 4 + r) * 256 + j * 16 + l16] = f2bs(S[j][r] * inv);
  }
  __syncthreads();

  // O = P (A-layout from LDS) * V (B-layout from VT)
  f32x4 O[4];
#pragma unroll
  for (int jn = 0; jn < 4; ++jn) O[jn] = fzero();
  for (int kk = 0; kk < 8; ++kk) {
    bf16x8 pf = *(const bf16x8*)&P[wave][l16 * 256 + kk * 32 + quad * 8];
#pragma unroll
    for (int jn = 0; jn < 4; ++jn) {
      bf16x8 vf = *(const bf16x8*)&VT[(jn * 16 + l16) * 256 + kk * 32 + quad * 8];
      O[jn] = mfma_bf16(pf, vf, O[jn]);
    }
  }
#pragma unroll
  for (int jn = 0; jn < 4; ++jn)
#pragma unroll
    for (int r = 0; r < 4; ++r) {
      int row = qr + quad * 4 + r;
      ao[(tok0 + row) * 768 + hh * 64 + jn * 16 + l16] = f2bs(O[jn][r]);
    }
}

// ---------------------------------------------------------------------------
// Time attention: softmax over T=32. Grid (l=256, head=12, b=2), 1 wave.
// token(t) = (b*32+t)*256 + l
// ---------------------------------------------------------------------------
__global__ __launch_bounds__(64) void attn_time(
    const short* __restrict__ qkv, short* __restrict__ ao)
{
  __shared__ __align__(16) short VT[64 * 32];   // VT[d][t]
  __shared__ __align__(16) short P[32 * 32];    // P[t_q][t_k]
  const int ll = blockIdx.x, hh = blockIdx.y, b = blockIdx.z;
  const int lane = threadIdx.x;
  const int quad = lane >> 4, l16 = lane & 15;
#define TOK(t) (((long)(b * 32 + (t))) * 256 + ll)

#pragma unroll
  for (int it = 0; it < 4; ++it) {
    int chunk = it * 64 + lane;
    int t = chunk >> 3, d8 = (chunk & 7) * 8;
    bf16x8 v = *(const bf16x8*)(qkv + TOK(t) * 2304 + 1536 + hh * 64 + d8);
#pragma unroll
    for (int e = 0; e < 8; ++e) VT[(d8 + e) * 32 + t] = v[e];
  }

  bf16x8 qf[2][2];
#pragma unroll
  for (int mi = 0; mi < 2; ++mi)
#pragma unroll
    for (int kk = 0; kk < 2; ++kk)
      qf[mi][kk] = *(const bf16x8*)(qkv + TOK(mi * 16 + l16) * 2304 + hh * 64 + kk * 32 + quad * 8);

  f32x4 S[2][2];
#pragma unroll
  for (int mi = 0; mi < 2; ++mi) { S[mi][0] = fzero(); S[mi][1] = fzero(); }
#pragma unroll
  for (int nj = 0; nj < 2; ++nj)
#pragma unroll
    for (int kk = 0; kk < 2; ++kk) {
      bf16x8 kf = *(const bf16x8*)(qkv + TOK(nj * 16 + l16) * 2304 + 768 + hh * 64 + kk * 32 + quad * 8);
#pragma unroll
      for (int mi = 0; mi < 2; ++mi)
        S[mi][nj] = mfma_bf16(qf[mi][kk], kf, S[mi][nj]);
    }

#pragma unroll
  for (int mi = 0; mi < 2; ++mi)
#pragma unroll
    for (int r = 0; r < 4; ++r) {
      float m = fmaxf(S[mi][0][r], S[mi][1][r]);
      m = quad16_max(m);
      float e0 = __expf((S[mi][0][r] - m) * 0.125f);
      float e1 = __expf((S[mi][1][r] - m) * 0.125f);
      float sum = quad16_sum(e0 + e1);
      float inv = 1.f / sum;
      P[(mi * 16 + quad * 4 + r) * 32 + l16]      = f2bs(e0 * inv);
      P[(mi * 16 + quad * 4 + r) * 32 + 16 + l16] = f2bs(e1 * inv);
    }
  __syncthreads();

  f32x4 O[2][4];
#pragma unroll
  for (int mi = 0; mi < 2; ++mi)
#pragma unroll
    for (int jn = 0; jn < 4; ++jn) O[mi][jn] = fzero();
#pragma unroll
  for (int mi = 0; mi < 2; ++mi) {
    bf16x8 pf = *(const bf16x8*)&P[(mi * 16 + l16) * 32 + quad * 8];
#pragma unroll
    for (int jn = 0; jn < 4; ++jn) {
      bf16x8 vf = *(const bf16x8*)&VT[(jn * 16 + l16) * 32 + quad * 8];
      O[mi][jn] = mfma_bf16(pf, vf, O[mi][jn]);
    }
  }
#pragma unroll
  for (int mi = 0; mi < 2; ++mi)
#pragma unroll
    for (int jn = 0; jn < 4; ++jn)
#pragma unroll
      for (int r = 0; r < 4; ++r) {
        int t = mi * 16 + quad * 4 + r;
        ao[TOK(t) * 768 + hh * 64 + jn * 16 + l16] = f2bs(O[mi][jn][r]);
      }
#undef TOK
}

// ---------------------------------------------------------------------------
extern "C" void kernel_launch(void* const* d_in, const int* in_sizes, int n_in,
                              void* d_out, int out_size, void* d_ws, size_t ws_size,
                              hipStream_t stream)
{
  const float* emb     = (const float*)d_in[0];
  const float* Wq_t    = (const float*)d_in[1];
  const float* Wk_t    = (const float*)d_in[2];
  const float* Wv_t    = (const float*)d_in[3];
  const float* Wo_t    = (const float*)d_in[4];
  const float* bo_t    = (const float*)d_in[5];
  const float* Wq_s    = (const float*)d_in[6];
  const float* Wk_s    = (const float*)d_in[7];
  const float* Wv_s    = (const float*)d_in[8];
  const float* Wo_s    = (const float*)d_in[9];
  const float* bo_s    = (const float*)d_in[10];
  const float* ln_t_sc = (const float*)d_in[11];
  const float* ln_t_bi = (const float*)d_in[12];
  const float* ln_s_sc = (const float*)d_in[13];
  const float* ln_s_bi = (const float*)d_in[14];
  const float* ln2_sc  = (const float*)d_in[15];
  const float* ln2_bi  = (const float*)d_in[16];
  const float* W1      = (const float*)d_in[17];
  const float* b1      = (const float*)d_in[18];
  const float* W2      = (const float*)d_in[19];
  const float* b2      = (const float*)d_in[20];

  const long M = 16384, D = 768, QN = 2304, F = 3072;
  char* ws = (char*)d_ws;
  size_t off = 0;
  auto alloc = [&](size_t b) { char* p = ws + off; off += (b + 255) & ~(size_t)255; return p; };
  short* qkvT_t = (short*)alloc((size_t)4 * QN * D * 2);   // 14.2 MB
  short* qkvT_s = (short*)alloc((size_t)4 * QN * D * 2);   // 14.2 MB
  short* woT_t  = (short*)alloc((size_t)4 * D * D * 2);    //  4.7 MB
  short* woT_s  = (short*)alloc((size_t)4 * D * D * 2);    //  4.7 MB
  short* w1T    = (short*)alloc((size_t)4 * F * D * 2);    // 18.9 MB
  short* w2T    = (short*)alloc((size_t)4 * D * F * 2);    // 18.9 MB
  short* xb     = (short*)alloc((size_t)M * D * 2);        // 25.2 MB
  short* aob    = (short*)alloc((size_t)M * D * 2);        // 25.2 MB
  short* big    = (short*)alloc((size_t)M * F * 2);        // 100.7 MB (qkv & ffn1)
  float* h = (float*)d_out;

  hipMemcpyAsync(h, emb, (size_t)M * D * 4, hipMemcpyDeviceToDevice, stream);

  // ---- weight prep: fp32 [K][N] -> bf16 [N][K], all 4 layers per launch ------
  transpose_w<<<dim3(24, 24, 4), 256, 0, stream>>>(Wq_t, qkvT_t,             768, 768,  D * D, QN * D);
  transpose_w<<<dim3(24, 24, 4), 256, 0, stream>>>(Wk_t, qkvT_t + D * D,     768, 768,  D * D, QN * D);
  transpose_w<<<dim3(24, 24, 4), 256, 0, stream>>>(Wv_t, qkvT_t + 2 * D * D, 768, 768,  D * D, QN * D);
  transpose_w<<<dim3(24, 24, 4), 256, 0, stream>>>(Wq_s, qkvT_s,             768, 768,  D * D, QN * D);
  transpose_w<<<dim3(24, 24, 4), 256, 0, stream>>>(Wk_s, qkvT_s + D * D,     768, 768,  D * D, QN * D);
  transpose_w<<<dim3(24, 24, 4), 256, 0, stream>>>(Wv_s, qkvT_s + 2 * D * D, 768, 768,  D * D, QN * D);
  transpose_w<<<dim3(24, 24, 4), 256, 0, stream>>>(Wo_t, woT_t,              768, 768,  D * D, D * D);
  transpose_w<<<dim3(24, 24, 4), 256, 0, stream>>>(Wo_s, woT_s,              768, 768,  D * D, D * D);
  transpose_w<<<dim3(96, 24, 4), 256, 0, stream>>>(W1,   w1T,                768, 3072, D * F, F * D);
  transpose_w<<<dim3(24, 96, 4), 256, 0, stream>>>(W2,   w2T,                3072, 768, F * D, D * F);

  // ---- layers ---------------------------------------------------------------
  for (int l = 0; l < 4; ++l) {
    // time attention block
    ln_kernel<<<16384, 256, 0, stream>>>(h, ln_t_sc + l * 768, ln_t_bi + l * 768, xb);
    gemm256<0><<<9 * 64, 512, 0, stream>>>(xb, qkvT_t + (long)l * QN * D,
        nullptr, nullptr, nullptr, big, 16384, 2304, 768, 9);
    attn_time<<<dim3(256, 12, 2), 64, 0, stream>>>(big, aob);
    gemm256<1><<<3 * 64, 512, 0, stream>>>(aob, woT_t + (long)l * D * D,
        bo_t + l * 768, h, h, nullptr, 16384, 768, 768, 3);
    // space attention block
    ln_kernel<<<16384, 256, 0, stream>>>(h, ln_s_sc + l * 768, ln_s_bi + l * 768, xb);
    gemm256<0><<<9 * 64, 512, 0, stream>>>(xb, qkvT_s + (long)l * QN * D,
        nullptr, nullptr, nullptr, big, 16384, 2304, 768, 9);
    attn_space<<<dim3(4, 12, 64), 256, 0, stream>>>(big, aob);
    gemm256<1><<<3 * 64, 512, 0, stream>>>(aob, woT_s + (long)l * D * D,
        bo_s + l * 768, h, h, nullptr, 16384, 768, 768, 3);
    // FFN block
    ln_kernel<<<16384, 256, 0, stream>>>(h, ln2_sc + l * 768, ln2_bi + l * 768, xb);
    gemm256<2><<<12 * 64, 512, 0, stream>>>(xb, w1T + (long)l * F * D,
        b1 + l * 3072, nullptr, nullptr, big, 16384, 3072, 768, 12);
    gemm256<1><<<3 * 64, 512, 0, stream>>>(big, w2T + (long)l * D * F,
        b2 + l * 768, h, h, nullptr, 16384, 768, 3072, 3);
  }
}

// Round 2
// 2553.951 us; speedup vs baseline: 1.0961x; 1.0702x over previous
//
#include <hip/hip_runtime.h>

// ---------------------------------------------------------------------------
// SpatioTemporalTransformerXL forward on gfx950.
//  - residual stream h stays fp32 in d_out, updated in place
//  - LN kernels emit bf16 x; all GEMMs are bf16 MFMA (16x16x32), fp32 acc
//  - GEMM: m201-style 256x256 tile, BK=64, 8 waves (2Mx4N), 2-buffer LDS
//    (128KB), 4 phases per K-tile {subtile ds_read || half-tile
//    global_load_lds -> barrier -> lgkmcnt(0) -> 16 MFMA -> barrier},
//    vmcnt(4) once per K-tile (counted, never 0 mid-loop), setprio around
//    MFMA, XOR granule swizzle (conflict-free), XCD-aware block swizzle
// ---------------------------------------------------------------------------

#define AS1 __attribute__((address_space(1)))
#define AS3 __attribute__((address_space(3)))

using bf16x8 = __attribute__((ext_vector_type(8))) short;   // 8 bf16 = 4 VGPRs
using f32x4  = __attribute__((ext_vector_type(4))) float;

__device__ __forceinline__ f32x4 mfma_bf16(bf16x8 a, bf16x8 b, f32x4 c) {
  return __builtin_amdgcn_mfma_f32_16x16x32_bf16(a, b, c, 0, 0, 0);
}

__device__ __forceinline__ void async16(const void* g, void* l) {
  __builtin_amdgcn_global_load_lds((const AS1 void*)g, (AS3 void*)l, 16, 0, 0);
}

// fp32 -> bf16 RNE
__device__ __forceinline__ short f2bs(float f) {
  union { float f; unsigned u; } x; x.f = f;
  unsigned r = x.u + 0x7fffu + ((x.u >> 16) & 1u);
  return (short)(r >> 16);
}

__device__ __forceinline__ f32x4 fzero() {
  f32x4 v; v[0] = 0.f; v[1] = 0.f; v[2] = 0.f; v[3] = 0.f; return v;
}

__device__ __forceinline__ float quad16_max(float v) {
  v = fmaxf(v, __shfl_xor(v, 1));
  v = fmaxf(v, __shfl_xor(v, 2));
  v = fmaxf(v, __shfl_xor(v, 4));
  v = fmaxf(v, __shfl_xor(v, 8));
  return v;
}
__device__ __forceinline__ float quad16_sum(float v) {
  v += __shfl_xor(v, 1); v += __shfl_xor(v, 2);
  v += __shfl_xor(v, 4); v += __shfl_xor(v, 8);
  return v;
}

// ---------------------------------------------------------------------------
// GEMM: C[M,N] = A[M,K](bf16) * BT[N,K]^T(bf16)  + epilogue
// MODE 0: outB = bf16(acc)                       (QKV projections)
// MODE 1: outF = acc + bias[col] + resid         (output proj / FFN2, fp32)
// MODE 2: outB = bf16(gelu_tanh(acc + bias))     (FFN1)
//
// Tile 256x256, BK=64, 8 waves = 2M x 4N, per-wave output 128x64
// (acc[8][4] 16x16 fragments).  LDS: 2 buffers x (A[256][64] | B[256][64]).
// Rows are 128B = 8 granules of 16B; granule g of row r stored at g ^ (r&7)
// (conflict-free ds_read_b128); global_load_lds inverts the swizzle in the
// per-lane global k-offset (LDS dest stays lane-linear).
//
// Per K-tile u (buffer u&1), 4 phases; per-wave subtile split:
//   P1: read a0 (a[0..3], 8xb128) + b0 (b[0..1], 4xb128); stage A-half0(u+1);
//       barrier; lgkmcnt(0); 16 MFMA (Q1 = a0 x b0); barrier
//   P2: read b1 (b[2..3], 4xb128);                stage A-half1(u+1); ... Q2
//   P3: read a1 (rows +64, 8xb128);               stage B-half0(u+2); ... Q3
//   P4: no reads (b0 kept in regs);               stage B-half1(u+2); Q4;
//       vmcnt(4) [tail: vmcnt(0)]; barrier
// Hazard: each overwritten half was fully read >=1 barrier earlier; the
// vmcnt(4)+barrier at P4 publishes tile u+1 landed before its P1 reads.
// ---------------------------------------------------------------------------
template<int MODE>
__global__ __launch_bounds__(512, 2) void gemm256(
    const short* __restrict__ A, const short* __restrict__ BT,
    const float* __restrict__ bias, const float* __restrict__ resid,
    float* __restrict__ outF, short* __restrict__ outB,
    int M, int N, int K, int nx)
{
  __shared__ __align__(16) short lds[65536];   // 128KB: 2 x (A 32KB | B 32KB)
  (void)M;
  const int tid  = threadIdx.x;
  const int lane = tid & 63, wave = tid >> 6;
  const int quad = lane >> 4, l16 = lane & 15;
  const int wm = wave >> 2, wn = wave & 3;     // 2 x 4 wave grid, 128x64 each

  // XCD-aware swizzle: 8 consecutive blocks (one per XCD) share a B panel;
  // per XCD, nx consecutive blocks share one A row-panel (L2-resident).
  const unsigned flat = blockIdx.x;
  const unsigned su = flat >> 3;
  const unsigned nxu = (unsigned)nx;
  const long bm0 = (long)((flat & 7u) + 8u * (su / nxu)) * 256;
  const long bn0 = (long)(su % nxu) * 256;

  // ---- staging geometry: 1 gload instr = 512thr x 16B = 64 rows x 128B ----
  const int trow = tid >> 3;                       // row within 8KB chunk
  const int tg   = ((tid & 7) ^ (trow & 7)) * 8;   // swizzle-inverted granule
  const short* As = A  + (bm0 + trow) * (long)K + tg;
  const short* Bs = BT + (bn0 + trow) * (long)K + tg;

  auto STAGE = [&](int tile, int isB, int half) {
    const short* sp = (isB ? Bs : As) + (long)half * 128 * K + (long)tile * 64;
    char* db = (char*)lds + (tile & 1) * 65536 + isB * 32768 + half * 16384
             + (tid << 4);
    async16(sp, db);
    async16(sp + ((long)K << 6), db + 8192);
  };

  // ---- fragment ds_read bases (shorts) ----
  const int swg   = (quad ^ (l16 & 7)) * 8;        // kk=0 swizzled granule off
  const int arow0 = wm * 128 + l16;
  const int brow0 = wn * 64 + l16;

  f32x4 acc[8][4];
#pragma unroll
  for (int i = 0; i < 8; ++i)
#pragma unroll
    for (int j = 0; j < 4; ++j) acc[i][j] = fzero();

  const int nt = K >> 6;                           // K/64: 12 or 48 (even, >=2)

  // prologue: tile0 all 4 halves + tile1 B halves; wait tile0; publish
  STAGE(0, 0, 0); STAGE(0, 0, 1); STAGE(0, 1, 0); STAGE(0, 1, 1);
  STAGE(1, 1, 0); STAGE(1, 1, 1);
  asm volatile("s_waitcnt vmcnt(4)" ::: "memory");
  __builtin_amdgcn_s_barrier();
  __builtin_amdgcn_sched_barrier(0);

  for (int u = 0; u < nt; ++u) {
    const short* bufA = lds + (u & 1) * 32768;
    const short* bufB = bufA + 16384;
    bf16x8 a[4][2], b[4][2];

    // ---------------- P1: a0 + b0 reads, stage A0(u+1), Q1 ----------------
#pragma unroll
    for (int i = 0; i < 4; ++i) {
      a[i][0] = *(const bf16x8*)(bufA + (arow0 + i * 16) * 64 + swg);
      a[i][1] = *(const bf16x8*)(bufA + (arow0 + i * 16) * 64 + (swg ^ 32));
    }
#pragma unroll
    for (int j = 0; j < 2; ++j) {
      b[j][0] = *(const bf16x8*)(bufB + (brow0 + j * 16) * 64 + swg);
      b[j][1] = *(const bf16x8*)(bufB + (brow0 + j * 16) * 64 + (swg ^ 32));
    }
    if (u + 1 < nt) STAGE(u + 1, 0, 0);
    asm volatile("s_waitcnt lgkmcnt(8)" ::: "memory");
    __builtin_amdgcn_s_barrier();
    asm volatile("s_waitcnt lgkmcnt(0)" ::: "memory");
    __builtin_amdgcn_sched_barrier(0);
    __builtin_amdgcn_s_setprio(1);
#pragma unroll
    for (int kk = 0; kk < 2; ++kk)
#pragma unroll
      for (int i = 0; i < 4; ++i)
#pragma unroll
        for (int j = 0; j < 2; ++j)
          acc[i][j] = mfma_bf16(a[i][kk], b[j][kk], acc[i][j]);
    __builtin_amdgcn_s_setprio(0);
    __builtin_amdgcn_s_barrier();

    // ---------------- P2: b1 reads, stage A1(u+1), Q2 ---------------------
#pragma unroll
    for (int j = 2; j < 4; ++j) {
      b[j][0] = *(const bf16x8*)(bufB + (brow0 + j * 16) * 64 + swg);
      b[j][1] = *(const bf16x8*)(bufB + (brow0 + j * 16) * 64 + (swg ^ 32));
    }
    if (u + 1 < nt) STAGE(u + 1, 0, 1);
    __builtin_amdgcn_s_barrier();
    asm volatile("s_waitcnt lgkmcnt(0)" ::: "memory");
    __builtin_amdgcn_sched_barrier(0);
    __builtin_amdgcn_s_setprio(1);
#pragma unroll
    for (int kk = 0; kk < 2; ++kk)
#pragma unroll
      for (int i = 0; i < 4; ++i)
#pragma unroll
        for (int j = 2; j < 4; ++j)
          acc[i][j] = mfma_bf16(a[i][kk], b[j][kk], acc[i][j]);
    __builtin_amdgcn_s_setprio(0);
    __builtin_amdgcn_s_barrier();

    // ---------------- P3: a1 reads (rows +64), stage B0(u+2), Q3 ----------
#pragma unroll
    for (int i = 0; i < 4; ++i) {
      a[i][0] = *(const bf16x8*)(bufA + (arow0 + 64 + i * 16) * 64 + swg);
      a[i][1] = *(const bf16x8*)(bufA + (arow0 + 64 + i * 16) * 64 + (swg ^ 32));
    }
    if (u + 2 < nt) STAGE(u + 2, 1, 0);
    __builtin_amdgcn_s_barrier();
    asm volatile("s_waitcnt lgkmcnt(0)" ::: "memory");
    __builtin_amdgcn_sched_barrier(0);
    __builtin_amdgcn_s_setprio(1);
#pragma unroll
    for (int kk = 0; kk < 2; ++kk)
#pragma unroll
      for (int i = 0; i < 4; ++i)
#pragma unroll
        for (int j = 2; j < 4; ++j)
          acc[4 + i][j] = mfma_bf16(a[i][kk], b[j][kk], acc[4 + i][j]);
    __builtin_amdgcn_s_setprio(0);
    __builtin_amdgcn_s_barrier();

    // ---------------- P4: no reads (b0 kept), stage B1(u+2), Q4 -----------
    if (u + 2 < nt) STAGE(u + 2, 1, 1);
    __builtin_amdgcn_s_barrier();
    __builtin_amdgcn_s_setprio(1);
#pragma unroll
    for (int kk = 0; kk < 2; ++kk)
#pragma unroll
      for (int i = 0; i < 4; ++i)
#pragma unroll
        for (int j = 0; j < 2; ++j)
          acc[4 + i][j] = mfma_bf16(a[i][kk], b[j][kk], acc[4 + i][j]);
    __builtin_amdgcn_s_setprio(0);
    if (u + 2 < nt) asm volatile("s_waitcnt vmcnt(4)" ::: "memory");
    else            asm volatile("s_waitcnt vmcnt(0)" ::: "memory");
    __builtin_amdgcn_s_barrier();
    __builtin_amdgcn_sched_barrier(0);
  }

  // ---- epilogue (C/D layout: col=l16, row=quad*4+r) ----
  const long rowbase = bm0 + wm * 128 + quad * 4;
  const long colbase = bn0 + wn * 64 + l16;
#pragma unroll
  for (int i = 0; i < 8; ++i)
#pragma unroll
    for (int j = 0; j < 4; ++j) {
      const long gc = colbase + j * 16;
#pragma unroll
      for (int r = 0; r < 4; ++r) {
        const long gr = rowbase + i * 16 + r;
        const size_t idx = (size_t)gr * N + gc;
        float v = acc[i][j][r];
        if (MODE == 0) {
          outB[idx] = f2bs(v);
        } else if (MODE == 1) {
          outF[idx] = v + bias[gc] + resid[idx];
        } else {
          float tt = v + bias[gc];
          float z = 0.7978845608f * (tt + 0.044715f * tt * tt * tt);
          float g = __fdividef(tt, 1.f + __expf(-2.f * z));
          outB[idx] = f2bs(g);
        }
      }
    }
}

// ---------------------------------------------------------------------------
// LayerNorm: h fp32 [16384,768] -> bf16 x, one block per row, 256 threads.
// ---------------------------------------------------------------------------
__global__ __launch_bounds__(256) void ln_kernel(
    const float* __restrict__ h, const float* __restrict__ sc,
    const float* __restrict__ bi, short* __restrict__ out)
{
  const int row = blockIdx.x, tid = threadIdx.x;
  const float* hr = h + (long)row * 768;
  float x0 = hr[tid], x1 = hr[tid + 256], x2 = hr[tid + 512];
  __shared__ float red[4];
  float s = x0 + x1 + x2;
#pragma unroll
  for (int m = 32; m >= 1; m >>= 1) s += __shfl_xor(s, m);
  if ((tid & 63) == 0) red[tid >> 6] = s;
  __syncthreads();
  float mean = (red[0] + red[1] + red[2] + red[3]) * (1.f / 768.f);
  float d0 = x0 - mean, d1 = x1 - mean, d2 = x2 - mean;
  float q = d0 * d0 + d1 * d1 + d2 * d2;
#pragma unroll
  for (int m = 32; m >= 1; m >>= 1) q += __shfl_xor(q, m);
  __syncthreads();
  if ((tid & 63) == 0) red[tid >> 6] = q;
  __syncthreads();
  float var = (red[0] + red[1] + red[2] + red[3]) * (1.f / 768.f);
  float inv = rsqrtf(var + 1e-5f);
  long o = (long)row * 768;
  out[o + tid]       = f2bs(d0 * inv * sc[tid]       + bi[tid]);
  out[o + tid + 256] = f2bs(d1 * inv * sc[tid + 256] + bi[tid + 256]);
  out[o + tid + 512] = f2bs(d2 * inv * sc[tid + 512] + bi[tid + 512]);
}

// ---------------------------------------------------------------------------
// Weight transpose + bf16 cast: in fp32 [Kd][Nd] -> out bf16 [Nd][Kd]
// z = layer index (batched over gridDim.z)
// ---------------------------------------------------------------------------
__global__ __launch_bounds__(256) void transpose_w(
    const float* __restrict__ in, short* __restrict__ out, int Kd, int Nd,
    long inStride, long outStride)
{
  __shared__ float t[32][33];
  const int z = blockIdx.z;
  in  += (long)z * inStride;
  out += (long)z * outStride;
  const int n0 = blockIdx.x * 32, k0 = blockIdx.y * 32;
  const int r = threadIdx.x >> 5, c = threadIdx.x & 31;
#pragma unroll
  for (int rr = 0; rr < 4; ++rr)
    t[r + rr * 8][c] = in[(long)(k0 + r + rr * 8) * Nd + n0 + c];
  __syncthreads();
#pragma unroll
  for (int rr = 0; rr < 4; ++rr)
    out[(long)(n0 + r + rr * 8) * Kd + k0 + c] = f2bs(t[c][r + rr * 8]);
}

// ---------------------------------------------------------------------------
// Space attention: softmax over L=256. Grid (qtile=4, head=12, b*t=64),
// 256 threads = 4 waves; each wave owns 16 q-rows. qkv row stride 2304:
// cols [0,768) Q, [768,1536) K, [1536,2304) V, packed h*64+d.
// ---------------------------------------------------------------------------
__global__ __launch_bounds__(256) void attn_space(
    const short* __restrict__ qkv, short* __restrict__ ao)
{
  __shared__ __align__(16) short VT[64 * 256];      // VT[d][l]
  __shared__ __align__(16) short P[4][16 * 256];    // per-wave P[q][l]
  const int qt = blockIdx.x, hh = blockIdx.y, bt = blockIdx.z;
  const long tok0 = (long)bt * 256;
  const int tid = threadIdx.x, wave = tid >> 6, lane = tid & 63;
  const int quad = lane >> 4, l16 = lane & 15;

  // stage V^T
#pragma unroll
  for (int it = 0; it < 8; ++it) {
    int chunk = it * 256 + tid;
    int vl = chunk >> 3, d8 = (chunk & 7) * 8;
    bf16x8 v = *(const bf16x8*)(qkv + (tok0 + vl) * 2304 + 1536 + hh * 64 + d8);
#pragma unroll
    for (int e = 0; e < 8; ++e) VT[(d8 + e) * 256 + vl] = v[e];
  }

  const int qr = qt * 64 + wave * 16;
  bf16x8 qf[2];
#pragma unroll
  for (int kk = 0; kk < 2; ++kk)
    qf[kk] = *(const bf16x8*)(qkv + (tok0 + qr + l16) * 2304 + hh * 64 + kk * 32 + quad * 8);

  f32x4 S[16];
#pragma unroll
  for (int j = 0; j < 16; ++j) S[j] = fzero();
#pragma unroll
  for (int j = 0; j < 16; ++j)
#pragma unroll
    for (int kk = 0; kk < 2; ++kk) {
      bf16x8 kf = *(const bf16x8*)(qkv + (tok0 + j * 16 + l16) * 2304 + 768 + hh * 64 + kk * 32 + quad * 8);
      S[j] = mfma_bf16(qf[kk], kf, S[j]);
    }

  // softmax rows quad*4+r  (C/D layout: col=l16, row=quad*4+reg)
#pragma unroll
  for (int r = 0; r < 4; ++r) {
    float m = -1e30f;
#pragma unroll
    for (int j = 0; j < 16; ++j) m = fmaxf(m, S[j][r]);
    m = quad16_max(m);
    float sum = 0.f;
#pragma unroll
    for (int j = 0; j < 16; ++j) {
      float e = __expf((S[j][r] - m) * 0.125f);
      S[j][r] = e; sum += e;
    }
    sum = quad16_sum(sum);
    float inv = 1.f / sum;
#pragma unroll
    for (int j = 0; j < 16; ++j)
      P[wave][(quad * 4 + r) * 256 + j * 16 + l16] = f2bs(S[j][r] * inv);
  }
  __syncthreads();

  // O = P (A-layout from LDS) * V (B-layout from VT)
  f32x4 O[4];
#pragma unroll
  for (int jn = 0; jn < 4; ++jn) O[jn] = fzero();
  for (int kk = 0; kk < 8; ++kk) {
    bf16x8 pf = *(const bf16x8*)&P[wave][l16 * 256 + kk * 32 + quad * 8];
#pragma unroll
    for (int jn = 0; jn < 4; ++jn) {
      bf16x8 vf = *(const bf16x8*)&VT[(jn * 16 + l16) * 256 + kk * 32 + quad * 8];
      O[jn] = mfma_bf16(pf, vf, O[jn]);
    }
  }
#pragma unroll
  for (int jn = 0; jn < 4; ++jn)
#pragma unroll
    for (int r = 0; r < 4; ++r) {
      int row = qr + quad * 4 + r;
      ao[(tok0 + row) * 768 + hh * 64 + jn * 16 + l16] = f2bs(O[jn][r]);
    }
}

// ---------------------------------------------------------------------------
// Time attention: softmax over T=32. Grid (l=256, head=12, b=2), 1 wave.
// token(t) = (b*32+t)*256 + l
// ---------------------------------------------------------------------------
__global__ __launch_bounds__(64) void attn_time(
    const short* __restrict__ qkv, short* __restrict__ ao)
{
  __shared__ __align__(16) short VT[64 * 32];   // VT[d][t]
  __shared__ __align__(16) short P[32 * 32];    // P[t_q][t_k]
  const int ll = blockIdx.x, hh = blockIdx.y, b = blockIdx.z;
  const int lane = threadIdx.x;
  const int quad = lane >> 4, l16 = lane & 15;
#define TOK(t) (((long)(b * 32 + (t))) * 256 + ll)

#pragma unroll
  for (int it = 0; it < 4; ++it) {
    int chunk = it * 64 + lane;
    int t = chunk >> 3, d8 = (chunk & 7) * 8;
    bf16x8 v = *(const bf16x8*)(qkv + TOK(t) * 2304 + 1536 + hh * 64 + d8);
#pragma unroll
    for (int e = 0; e < 8; ++e) VT[(d8 + e) * 32 + t] = v[e];
  }

  bf16x8 qf[2][2];
#pragma unroll
  for (int mi = 0; mi < 2; ++mi)
#pragma unroll
    for (int kk = 0; kk < 2; ++kk)
      qf[mi][kk] = *(const bf16x8*)(qkv + TOK(mi * 16 + l16) * 2304 + hh * 64 + kk * 32 + quad * 8);

  f32x4 S[2][2];
#pragma unroll
  for (int mi = 0; mi < 2; ++mi) { S[mi][0] = fzero(); S[mi][1] = fzero(); }
#pragma unroll
  for (int nj = 0; nj < 2; ++nj)
#pragma unroll
    for (int kk = 0; kk < 2; ++kk) {
      bf16x8 kf = *(const bf16x8*)(qkv + TOK(nj * 16 + l16) * 2304 + 768 + hh * 64 + kk * 32 + quad * 8);
#pragma unroll
      for (int mi = 0; mi < 2; ++mi)
        S[mi][nj] = mfma_bf16(qf[mi][kk], kf, S[mi][nj]);
    }

#pragma unroll
  for (int mi = 0; mi < 2; ++mi)
#pragma unroll
    for (int r = 0; r < 4; ++r) {
      float m = fmaxf(S[mi][0][r], S[mi][1][r]);
      m = quad16_max(m);
      float e0 = __expf((S[mi][0][r] - m) * 0.125f);
      float e1 = __expf((S[mi][1][r] - m) * 0.125f);
      float sum = quad16_sum(e0 + e1);
      float inv = 1.f / sum;
      P[(mi * 16 + quad * 4 + r) * 32 + l16]      = f2bs(e0 * inv);
      P[(mi * 16 + quad * 4 + r) * 32 + 16 + l16] = f2bs(e1 * inv);
    }
  __syncthreads();

  f32x4 O[2][4];
#pragma unroll
  for (int mi = 0; mi < 2; ++mi)
#pragma unroll
    for (int jn = 0; jn < 4; ++jn) O[mi][jn] = fzero();
#pragma unroll
  for (int mi = 0; mi < 2; ++mi) {
    bf16x8 pf = *(const bf16x8*)&P[(mi * 16 + l16) * 32 + quad * 8];
#pragma unroll
    for (int jn = 0; jn < 4; ++jn) {
      bf16x8 vf = *(const bf16x8*)&VT[(jn * 16 + l16) * 32 + quad * 8];
      O[mi][jn] = mfma_bf16(pf, vf, O[mi][jn]);
    }
  }
#pragma unroll
  for (int mi = 0; mi < 2; ++mi)
#pragma unroll
    for (int jn = 0; jn < 4; ++jn)
#pragma unroll
      for (int r = 0; r < 4; ++r) {
        int t = mi * 16 + quad * 4 + r;
        ao[TOK(t) * 768 + hh * 64 + jn * 16 + l16] = f2bs(O[mi][jn][r]);
      }
#undef TOK
}

// ---------------------------------------------------------------------------
extern "C" void kernel_launch(void* const* d_in, const int* in_sizes, int n_in,
                              void* d_out, int out_size, void* d_ws, size_t ws_size,
                              hipStream_t stream)
{
  const float* emb     = (const float*)d_in[0];
  const float* Wq_t    = (const float*)d_in[1];
  const float* Wk_t    = (const float*)d_in[2];
  const float* Wv_t    = (const float*)d_in[3];
  const float* Wo_t    = (const float*)d_in[4];
  const float* bo_t    = (const float*)d_in[5];
  const float* Wq_s    = (const float*)d_in[6];
  const float* Wk_s    = (const float*)d_in[7];
  const float* Wv_s    = (const float*)d_in[8];
  const float* Wo_s    = (const float*)d_in[9];
  const float* bo_s    = (const float*)d_in[10];
  const float* ln_t_sc = (const float*)d_in[11];
  const float* ln_t_bi = (const float*)d_in[12];
  const float* ln_s_sc = (const float*)d_in[13];
  const float* ln_s_bi = (const float*)d_in[14];
  const float* ln2_sc  = (const float*)d_in[15];
  const float* ln2_bi  = (const float*)d_in[16];
  const float* W1      = (const float*)d_in[17];
  const float* b1      = (const float*)d_in[18];
  const float* W2      = (const float*)d_in[19];
  const float* b2      = (const float*)d_in[20];

  const long M = 16384, D = 768, QN = 2304, F = 3072;
  char* ws = (char*)d_ws;
  size_t off = 0;
  auto alloc = [&](size_t b) { char* p = ws + off; off += (b + 255) & ~(size_t)255; return p; };
  short* qkvT_t = (short*)alloc((size_t)4 * QN * D * 2);   // 14.2 MB
  short* qkvT_s = (short*)alloc((size_t)4 * QN * D * 2);   // 14.2 MB
  short* woT_t  = (short*)alloc((size_t)4 * D * D * 2);    //  4.7 MB
  short* woT_s  = (short*)alloc((size_t)4 * D * D * 2);    //  4.7 MB
  short* w1T    = (short*)alloc((size_t)4 * F * D * 2);    // 18.9 MB
  short* w2T    = (short*)alloc((size_t)4 * D * F * 2);    // 18.9 MB
  short* xb     = (short*)alloc((size_t)M * D * 2);        // 25.2 MB
  short* aob    = (short*)alloc((size_t)M * D * 2);        // 25.2 MB
  short* big    = (short*)alloc((size_t)M * F * 2);        // 100.7 MB (qkv & ffn1)
  float* h = (float*)d_out;

  hipMemcpyAsync(h, emb, (size_t)M * D * 4, hipMemcpyDeviceToDevice, stream);

  // ---- weight prep: fp32 [K][N] -> bf16 [N][K], all 4 layers per launch ------
  transpose_w<<<dim3(24, 24, 4), 256, 0, stream>>>(Wq_t, qkvT_t,             768, 768,  D * D, QN * D);
  transpose_w<<<dim3(24, 24, 4), 256, 0, stream>>>(Wk_t, qkvT_t + D * D,     768, 768,  D * D, QN * D);
  transpose_w<<<dim3(24, 24, 4), 256, 0, stream>>>(Wv_t, qkvT_t + 2 * D * D, 768, 768,  D * D, QN * D);
  transpose_w<<<dim3(24, 24, 4), 256, 0, stream>>>(Wq_s, qkvT_s,             768, 768,  D * D, QN * D);
  transpose_w<<<dim3(24, 24, 4), 256, 0, stream>>>(Wk_s, qkvT_s + D * D,     768, 768,  D * D, QN * D);
  transpose_w<<<dim3(24, 24, 4), 256, 0, stream>>>(Wv_s, qkvT_s + 2 * D * D, 768, 768,  D * D, QN * D);
  transpose_w<<<dim3(24, 24, 4), 256, 0, stream>>>(Wo_t, woT_t,              768, 768,  D * D, D * D);
  transpose_w<<<dim3(24, 24, 4), 256, 0, stream>>>(Wo_s, woT_s,              768, 768,  D * D, D * D);
  transpose_w<<<dim3(96, 24, 4), 256, 0, stream>>>(W1,   w1T,                768, 3072, D * F, F * D);
  transpose_w<<<dim3(24, 96, 4), 256, 0, stream>>>(W2,   w2T,                3072, 768, F * D, D * F);

  // ---- layers ---------------------------------------------------------------
  for (int l = 0; l < 4; ++l) {
    // time attention block
    ln_kernel<<<16384, 256, 0, stream>>>(h, ln_t_sc + l * 768, ln_t_bi + l * 768, xb);
    gemm256<0><<<9 * 64, 512, 0, stream>>>(xb, qkvT_t + (long)l * QN * D,
        nullptr, nullptr, nullptr, big, 16384, 2304, 768, 9);
    attn_time<<<dim3(256, 12, 2), 64, 0, stream>>>(big, aob);
    gemm256<1><<<3 * 64, 512, 0, stream>>>(aob, woT_t + (long)l * D * D,
        bo_t + l * 768, h, h, nullptr, 16384, 768, 768, 3);
    // space attention block
    ln_kernel<<<16384, 256, 0, stream>>>(h, ln_s_sc + l * 768, ln_s_bi + l * 768, xb);
    gemm256<0><<<9 * 64, 512, 0, stream>>>(xb, qkvT_s + (long)l * QN * D,
        nullptr, nullptr, nullptr, big, 16384, 2304, 768, 9);
    attn_space<<<dim3(4, 12, 64), 256, 0, stream>>>(big, aob);
    gemm256<1><<<3 * 64, 512, 0, stream>>>(aob, woT_s + (long)l * D * D,
        bo_s + l * 768, h, h, nullptr, 16384, 768, 768, 3);
    // FFN block
    ln_kernel<<<16384, 256, 0, stream>>>(h, ln2_sc + l * 768, ln2_bi + l * 768, xb);
    gemm256<2><<<12 * 64, 512, 0, stream>>>(xb, w1T + (long)l * F * D,
        b1 + l * 3072, nullptr, nullptr, big, 16384, 3072, 768, 12);
    gemm256<1><<<3 * 64, 512, 0, stream>>>(big, w2T + (long)l * D * F,
        b2 + l * 768, h, h, nullptr, 16384, 768, 3072, 3);
  }
}

// Round 3
// 2545.325 us; speedup vs baseline: 1.0998x; 1.0034x over previous
//
#include <hip/hip_runtime.h>

// ---------------------------------------------------------------------------
// SpatioTemporalTransformerXL forward on gfx950.
//  - residual stream h stays fp32 in d_out, updated in place
//  - LN kernels emit bf16 x; all GEMMs are bf16 MFMA (16x16x32), fp32 acc
//  - GEMM: 256x256 tile, BK=64, 8 waves (2Mx4N), 2-buffer LDS (128KB),
//    4 soft phases per K-tile; ALL stages target the opposite buffer
//    (tile u+1), so only ONE barrier per K-tile is needed (vmcnt(0)+bar at
//    tile end publishes the staged tile). Waves free-run within a tile ->
//    cross-wave MFMA/LDS-read overlap. setprio around MFMA clusters,
//    XOR granule swizzle (conflict-free), XCD-aware block swizzle.
// ---------------------------------------------------------------------------

#define AS1 __attribute__((address_space(1)))
#define AS3 __attribute__((address_space(3)))

using bf16x8 = __attribute__((ext_vector_type(8))) short;   // 8 bf16 = 4 VGPRs
using f32x4  = __attribute__((ext_vector_type(4))) float;

__device__ __forceinline__ f32x4 mfma_bf16(bf16x8 a, bf16x8 b, f32x4 c) {
  return __builtin_amdgcn_mfma_f32_16x16x32_bf16(a, b, c, 0, 0, 0);
}

__device__ __forceinline__ void async16(const void* g, void* l) {
  __builtin_amdgcn_global_load_lds((const AS1 void*)g, (AS3 void*)l, 16, 0, 0);
}

// fp32 -> bf16 RNE
__device__ __forceinline__ short f2bs(float f) {
  union { float f; unsigned u; } x; x.f = f;
  unsigned r = x.u + 0x7fffu + ((x.u >> 16) & 1u);
  return (short)(r >> 16);
}

__device__ __forceinline__ f32x4 fzero() {
  f32x4 v; v[0] = 0.f; v[1] = 0.f; v[2] = 0.f; v[3] = 0.f; return v;
}

__device__ __forceinline__ float quad16_max(float v) {
  v = fmaxf(v, __shfl_xor(v, 1));
  v = fmaxf(v, __shfl_xor(v, 2));
  v = fmaxf(v, __shfl_xor(v, 4));
  v = fmaxf(v, __shfl_xor(v, 8));
  return v;
}
__device__ __forceinline__ float quad16_sum(float v) {
  v += __shfl_xor(v, 1); v += __shfl_xor(v, 2);
  v += __shfl_xor(v, 4); v += __shfl_xor(v, 8);
  return v;
}

// ---------------------------------------------------------------------------
// GEMM: C[M,N] = A[M,K](bf16) * BT[N,K]^T(bf16)  + epilogue
// MODE 0: outB = bf16(acc)                       (QKV projections)
// MODE 1: outF = acc + bias[col] + resid         (output proj / FFN2, fp32)
// MODE 2: outB = bf16(gelu_tanh(acc + bias))     (FFN1)
//
// Tile 256x256, BK=64, 8 waves = 2M x 4N, per-wave output 128x64
// (acc[8][4] 16x16 fragments).  LDS: 2 buffers x (A[256][64] | B[256][64]).
// Rows are 128B = 8 granules of 16B; granule g of row r stored at g ^ (r&7)
// (conflict-free ds_read_b128); global_load_lds inverts the swizzle in the
// per-lane global k-offset (LDS dest stays lane-linear).
//
// Per K-tile u (read buffer u&1), 4 soft phases, NO intra-tile barriers:
//   P1: STAGE A0(u+1); read a0(8xb128)+b0(4); lgkm(0); Q1 = a0 x b0
//   P2: STAGE A1(u+1); read b1(4);            lgkm(0); Q2 = a0 x b1
//   P3: STAGE B0(u+1); read a1(8);            lgkm(0); Q3 = a1 x b1
//   P4: STAGE B1(u+1);                                 Q4 = a1 x b0
//       vmcnt(0); s_barrier     <- publishes tile u+1; sole barrier/tile
// Safety for ANY intra-tile wave skew: reads hit buffer u&1 only, stages hit
// buffer ^1 only; tile u-1's reads of buffer ^1 completed before each wave
// reached the end-of-tile barrier of u-1 (lgkm(0) precedes it in program
// order); readers of tile u+1 start only after vmcnt(0)+barrier.
// ---------------------------------------------------------------------------
template<int MODE>
__global__ __launch_bounds__(512, 2) void gemm256(
    const short* __restrict__ A, const short* __restrict__ BT,
    const float* __restrict__ bias, const float* __restrict__ resid,
    float* __restrict__ outF, short* __restrict__ outB,
    int M, int N, int K, int nx)
{
  __shared__ __align__(16) short lds[65536];   // 128KB: 2 x (A 32KB | B 32KB)
  (void)M;
  const int tid  = threadIdx.x;
  const int lane = tid & 63, wave = tid >> 6;
  const int quad = lane >> 4, l16 = lane & 15;
  const int wm = wave >> 2, wn = wave & 3;     // 2 x 4 wave grid, 128x64 each

  // XCD-aware swizzle: 8 consecutive blocks (one per XCD) share a B panel;
  // per XCD, nx consecutive blocks share one A row-panel (L2-resident).
  const unsigned flat = blockIdx.x;
  const unsigned su = flat >> 3;
  const unsigned nxu = (unsigned)nx;
  const long bm0 = (long)((flat & 7u) + 8u * (su / nxu)) * 256;
  const long bn0 = (long)(su % nxu) * 256;

  // ---- staging geometry: 1 gload instr = 512thr x 16B = 64 rows x 128B ----
  const int trow = tid >> 3;                       // row within 8KB chunk
  const int tg   = ((tid & 7) ^ (trow & 7)) * 8;   // swizzle-inverted granule
  const short* As = A  + (bm0 + trow) * (long)K + tg;
  const short* Bs = BT + (bn0 + trow) * (long)K + tg;

  auto STAGE = [&](int tile, int isB, int half) {
    const short* sp = (isB ? Bs : As) + (long)half * 128 * K + (long)tile * 64;
    char* db = (char*)lds + (tile & 1) * 65536 + isB * 32768 + half * 16384
             + (tid << 4);
    async16(sp, db);
    async16(sp + ((long)K << 6), db + 8192);
  };

  // ---- fragment ds_read bases (shorts) ----
  const int swg   = (quad ^ (l16 & 7)) * 8;        // kk=0 swizzled granule off
  const int arow0 = wm * 128 + l16;
  const int brow0 = wn * 64 + l16;

  f32x4 acc[8][4];
#pragma unroll
  for (int i = 0; i < 8; ++i)
#pragma unroll
    for (int j = 0; j < 4; ++j) acc[i][j] = fzero();

  const int nt = K >> 6;                           // K/64: 12 or 48

  // prologue: stage tile0 (both buffers' worth not needed; just tile0), publish
  STAGE(0, 0, 0); STAGE(0, 0, 1); STAGE(0, 1, 0); STAGE(0, 1, 1);
  asm volatile("s_waitcnt vmcnt(0)" ::: "memory");
  __builtin_amdgcn_s_barrier();
  __builtin_amdgcn_sched_barrier(0);

  for (int u = 0; u < nt; ++u) {
    const short* bufA = lds + (u & 1) * 32768;
    const short* bufB = bufA + 16384;
    const bool pf = (u + 1 < nt);
    bf16x8 a[4][2], b[4][2];

    // ---------------- P1: stage A0(u+1) | read a0,b0 | Q1 ------------------
    if (pf) STAGE(u + 1, 0, 0);
#pragma unroll
    for (int i = 0; i < 4; ++i) {
      a[i][0] = *(const bf16x8*)(bufA + (arow0 + i * 16) * 64 + swg);
      a[i][1] = *(const bf16x8*)(bufA + (arow0 + i * 16) * 64 + (swg ^ 32));
    }
#pragma unroll
    for (int j = 0; j < 2; ++j) {
      b[j][0] = *(const bf16x8*)(bufB + (brow0 + j * 16) * 64 + swg);
      b[j][1] = *(const bf16x8*)(bufB + (brow0 + j * 16) * 64 + (swg ^ 32));
    }
    asm volatile("s_waitcnt lgkmcnt(0)" ::: "memory");
    __builtin_amdgcn_sched_barrier(0);
    __builtin_amdgcn_s_setprio(1);
#pragma unroll
    for (int kk = 0; kk < 2; ++kk)
#pragma unroll
      for (int i = 0; i < 4; ++i)
#pragma unroll
        for (int j = 0; j < 2; ++j)
          acc[i][j] = mfma_bf16(a[i][kk], b[j][kk], acc[i][j]);
    __builtin_amdgcn_s_setprio(0);

    // ---------------- P2: stage A1(u+1) | read b1 | Q2 ---------------------
    if (pf) STAGE(u + 1, 0, 1);
#pragma unroll
    for (int j = 2; j < 4; ++j) {
      b[j][0] = *(const bf16x8*)(bufB + (brow0 + j * 16) * 64 + swg);
      b[j][1] = *(const bf16x8*)(bufB + (brow0 + j * 16) * 64 + (swg ^ 32));
    }
    asm volatile("s_waitcnt lgkmcnt(0)" ::: "memory");
    __builtin_amdgcn_sched_barrier(0);
    __builtin_amdgcn_s_setprio(1);
#pragma unroll
    for (int kk = 0; kk < 2; ++kk)
#pragma unroll
      for (int i = 0; i < 4; ++i)
#pragma unroll
        for (int j = 2; j < 4; ++j)
          acc[i][j] = mfma_bf16(a[i][kk], b[j][kk], acc[i][j]);
    __builtin_amdgcn_s_setprio(0);

    // ---------------- P3: stage B0(u+1) | read a1 | Q3 ---------------------
    if (pf) STAGE(u + 1, 1, 0);
#pragma unroll
    for (int i = 0; i < 4; ++i) {
      a[i][0] = *(const bf16x8*)(bufA + (arow0 + 64 + i * 16) * 64 + swg);
      a[i][1] = *(const bf16x8*)(bufA + (arow0 + 64 + i * 16) * 64 + (swg ^ 32));
    }
    asm volatile("s_waitcnt lgkmcnt(0)" ::: "memory");
    __builtin_amdgcn_sched_barrier(0);
    __builtin_amdgcn_s_setprio(1);
#pragma unroll
    for (int kk = 0; kk < 2; ++kk)
#pragma unroll
      for (int i = 0; i < 4; ++i)
#pragma unroll
        for (int j = 2; j < 4; ++j)
          acc[4 + i][j] = mfma_bf16(a[i][kk], b[j][kk], acc[4 + i][j]);
    __builtin_amdgcn_s_setprio(0);

    // ---------------- P4: stage B1(u+1) | Q4 | publish ---------------------
    if (pf) STAGE(u + 1, 1, 1);
    __builtin_amdgcn_s_setprio(1);
#pragma unroll
    for (int kk = 0; kk < 2; ++kk)
#pragma unroll
      for (int i = 0; i < 4; ++i)
#pragma unroll
        for (int j = 0; j < 2; ++j)
          acc[4 + i][j] = mfma_bf16(a[i][kk], b[j][kk], acc[4 + i][j]);
    __builtin_amdgcn_s_setprio(0);
    asm volatile("s_waitcnt vmcnt(0)" ::: "memory");
    __builtin_amdgcn_s_barrier();
    __builtin_amdgcn_sched_barrier(0);
  }

  // ---- epilogue (C/D layout: col=l16, row=quad*4+r) ----
  const long rowbase = bm0 + wm * 128 + quad * 4;
  const long colbase = bn0 + wn * 64 + l16;
#pragma unroll
  for (int i = 0; i < 8; ++i)
#pragma unroll
    for (int j = 0; j < 4; ++j) {
      const long gc = colbase + j * 16;
#pragma unroll
      for (int r = 0; r < 4; ++r) {
        const long gr = rowbase + i * 16 + r;
        const size_t idx = (size_t)gr * N + gc;
        float v = acc[i][j][r];
        if (MODE == 0) {
          outB[idx] = f2bs(v);
        } else if (MODE == 1) {
          outF[idx] = v + bias[gc] + resid[idx];
        } else {
          float tt = v + bias[gc];
          float z = 0.7978845608f * (tt + 0.044715f * tt * tt * tt);
          float g = __fdividef(tt, 1.f + __expf(-2.f * z));
          outB[idx] = f2bs(g);
        }
      }
    }
}

// ---------------------------------------------------------------------------
// LayerNorm: h fp32 [16384,768] -> bf16 x, one block per row, 256 threads.
// ---------------------------------------------------------------------------
__global__ __launch_bounds__(256) void ln_kernel(
    const float* __restrict__ h, const float* __restrict__ sc,
    const float* __restrict__ bi, short* __restrict__ out)
{
  const int row = blockIdx.x, tid = threadIdx.x;
  const float* hr = h + (long)row * 768;
  float x0 = hr[tid], x1 = hr[tid + 256], x2 = hr[tid + 512];
  __shared__ float red[4];
  float s = x0 + x1 + x2;
#pragma unroll
  for (int m = 32; m >= 1; m >>= 1) s += __shfl_xor(s, m);
  if ((tid & 63) == 0) red[tid >> 6] = s;
  __syncthreads();
  float mean = (red[0] + red[1] + red[2] + red[3]) * (1.f / 768.f);
  float d0 = x0 - mean, d1 = x1 - mean, d2 = x2 - mean;
  float q = d0 * d0 + d1 * d1 + d2 * d2;
#pragma unroll
  for (int m = 32; m >= 1; m >>= 1) q += __shfl_xor(q, m);
  __syncthreads();
  if ((tid & 63) == 0) red[tid >> 6] = q;
  __syncthreads();
  float var = (red[0] + red[1] + red[2] + red[3]) * (1.f / 768.f);
  float inv = rsqrtf(var + 1e-5f);
  long o = (long)row * 768;
  out[o + tid]       = f2bs(d0 * inv * sc[tid]       + bi[tid]);
  out[o + tid + 256] = f2bs(d1 * inv * sc[tid + 256] + bi[tid + 256]);
  out[o + tid + 512] = f2bs(d2 * inv * sc[tid + 512] + bi[tid + 512]);
}

// ---------------------------------------------------------------------------
// Weight transpose + bf16 cast: in fp32 [Kd][Nd] -> out bf16 [Nd][Kd]
// z = layer index (batched over gridDim.z)
// ---------------------------------------------------------------------------
__global__ __launch_bounds__(256) void transpose_w(
    const float* __restrict__ in, short* __restrict__ out, int Kd, int Nd,
    long inStride, long outStride)
{
  __shared__ float t[32][33];
  const int z = blockIdx.z;
  in  += (long)z * inStride;
  out += (long)z * outStride;
  const int n0 = blockIdx.x * 32, k0 = blockIdx.y * 32;
  const int r = threadIdx.x >> 5, c = threadIdx.x & 31;
#pragma unroll
  for (int rr = 0; rr < 4; ++rr)
    t[r + rr * 8][c] = in[(long)(k0 + r + rr * 8) * Nd + n0 + c];
  __syncthreads();
#pragma unroll
  for (int rr = 0; rr < 4; ++rr)
    out[(long)(n0 + r + rr * 8) * Kd + k0 + c] = f2bs(t[c][r + rr * 8]);
}

// ---------------------------------------------------------------------------
// Space attention: softmax over L=256. Grid (qtile=4, head=12, b*t=64),
// 256 threads = 4 waves; each wave owns 16 q-rows. qkv row stride 2304:
// cols [0,768) Q, [768,1536) K, [1536,2304) V, packed h*64+d.
// ---------------------------------------------------------------------------
__global__ __launch_bounds__(256) void attn_space(
    const short* __restrict__ qkv, short* __restrict__ ao)
{
  __shared__ __align__(16) short VT[64 * 256];      // VT[d][l]
  __shared__ __align__(16) short P[4][16 * 256];    // per-wave P[q][l]
  const int qt = blockIdx.x, hh = blockIdx.y, bt = blockIdx.z;
  const long tok0 = (long)bt * 256;
  const int tid = threadIdx.x, wave = tid >> 6, lane = tid & 63;
  const int quad = lane >> 4, l16 = lane & 15;

  // stage V^T
#pragma unroll
  for (int it = 0; it < 8; ++it) {
    int chunk = it * 256 + tid;
    int vl = chunk >> 3, d8 = (chunk & 7) * 8;
    bf16x8 v = *(const bf16x8*)(qkv + (tok0 + vl) * 2304 + 1536 + hh * 64 + d8);
#pragma unroll
    for (int e = 0; e < 8; ++e) VT[(d8 + e) * 256 + vl] = v[e];
  }

  const int qr = qt * 64 + wave * 16;
  bf16x8 qf[2];
#pragma unroll
  for (int kk = 0; kk < 2; ++kk)
    qf[kk] = *(const bf16x8*)(qkv + (tok0 + qr + l16) * 2304 + hh * 64 + kk * 32 + quad * 8);

  f32x4 S[16];
#pragma unroll
  for (int j = 0; j < 16; ++j) S[j] = fzero();
#pragma unroll
  for (int j = 0; j < 16; ++j)
#pragma unroll
    for (int kk = 0; kk < 2; ++kk) {
      bf16x8 kf = *(const bf16x8*)(qkv + (tok0 + j * 16 + l16) * 2304 + 768 + hh * 64 + kk * 32 + quad * 8);
      S[j] = mfma_bf16(qf[kk], kf, S[j]);
    }

  // softmax rows quad*4+r  (C/D layout: col=l16, row=quad*4+reg)
#pragma unroll
  for (int r = 0; r < 4; ++r) {
    float m = -1e30f;
#pragma unroll
    for (int j = 0; j < 16; ++j) m = fmaxf(m, S[j][r]);
    m = quad16_max(m);
    float sum = 0.f;
#pragma unroll
    for (int j = 0; j < 16; ++j) {
      float e = __expf((S[j][r] - m) * 0.125f);
      S[j][r] = e; sum += e;
    }
    sum = quad16_sum(sum);
    float inv = 1.f / sum;
#pragma unroll
    for (int j = 0; j < 16; ++j)
      P[wave][(quad * 4 + r) * 256 + j * 16 + l16] = f2bs(S[j][r] * inv);
  }
  __syncthreads();

  // O = P (A-layout from LDS) * V (B-layout from VT)
  f32x4 O[4];
#pragma unroll
  for (int jn = 0; jn < 4; ++jn) O[jn] = fzero();
  for (int kk = 0; kk < 8; ++kk) {
    bf16x8 pf = *(const bf16x8*)&P[wave][l16 * 256 + kk * 32 + quad * 8];
#pragma unroll
    for (int jn = 0; jn < 4; ++jn) {
      bf16x8 vf = *(const bf16x8*)&VT[(jn * 16 + l16) * 256 + kk * 32 + quad * 8];
      O[jn] = mfma_bf16(pf, vf, O[jn]);
    }
  }
#pragma unroll
  for (int jn = 0; jn < 4; ++jn)
#pragma unroll
    for (int r = 0; r < 4; ++r) {
      int row = qr + quad * 4 + r;
      ao[(tok0 + row) * 768 + hh * 64 + jn * 16 + l16] = f2bs(O[jn][r]);
    }
}

// ---------------------------------------------------------------------------
// Time attention: softmax over T=32. Grid (l=256, head=12, b=2), 1 wave.
// token(t) = (b*32+t)*256 + l
// ---------------------------------------------------------------------------
__global__ __launch_bounds__(64) void attn_time(
    const short* __restrict__ qkv, short* __restrict__ ao)
{
  __shared__ __align__(16) short VT[64 * 32];   // VT[d][t]
  __shared__ __align__(16) short P[32 * 32];    // P[t_q][t_k]
  const int ll = blockIdx.x, hh = blockIdx.y, b = blockIdx.z;
  const int lane = threadIdx.x;
  const int quad = lane >> 4, l16 = lane & 15;
#define TOK(t) (((long)(b * 32 + (t))) * 256 + ll)

#pragma unroll
  for (int it = 0; it < 4; ++it) {
    int chunk = it * 64 + lane;
    int t = chunk >> 3, d8 = (chunk & 7) * 8;
    bf16x8 v = *(const bf16x8*)(qkv + TOK(t) * 2304 + 1536 + hh * 64 + d8);
#pragma unroll
    for (int e = 0; e < 8; ++e) VT[(d8 + e) * 32 + t] = v[e];
  }

  bf16x8 qf[2][2];
#pragma unroll
  for (int mi = 0; mi < 2; ++mi)
#pragma unroll
    for (int kk = 0; kk < 2; ++kk)
      qf[mi][kk] = *(const bf16x8*)(qkv + TOK(mi * 16 + l16) * 2304 + hh * 64 + kk * 32 + quad * 8);

  f32x4 S[2][2];
#pragma unroll
  for (int mi = 0; mi < 2; ++mi) { S[mi][0] = fzero(); S[mi][1] = fzero(); }
#pragma unroll
  for (int nj = 0; nj < 2; ++nj)
#pragma unroll
    for (int kk = 0; kk < 2; ++kk) {
      bf16x8 kf = *(const bf16x8*)(qkv + TOK(nj * 16 + l16) * 2304 + 768 + hh * 64 + kk * 32 + quad * 8);
#pragma unroll
      for (int mi = 0; mi < 2; ++mi)
        S[mi][nj] = mfma_bf16(qf[mi][kk], kf, S[mi][nj]);
    }

#pragma unroll
  for (int mi = 0; mi < 2; ++mi)
#pragma unroll
    for (int r = 0; r < 4; ++r) {
      float m = fmaxf(S[mi][0][r], S[mi][1][r]);
      m = quad16_max(m);
      float e0 = __expf((S[mi][0][r] - m) * 0.125f);
      float e1 = __expf((S[mi][1][r] - m) * 0.125f);
      float sum = quad16_sum(e0 + e1);
      float inv = 1.f / sum;
      P[(mi * 16 + quad * 4 + r) * 32 + l16]      = f2bs(e0 * inv);
      P[(mi * 16 + quad * 4 + r) * 32 + 16 + l16] = f2bs(e1 * inv);
    }
  __syncthreads();

  f32x4 O[2][4];
#pragma unroll
  for (int mi = 0; mi < 2; ++mi)
#pragma unroll
    for (int jn = 0; jn < 4; ++jn) O[mi][jn] = fzero();
#pragma unroll
  for (int mi = 0; mi < 2; ++mi) {
    bf16x8 pf = *(const bf16x8*)&P[(mi * 16 + l16) * 32 + quad * 8];
#pragma unroll
    for (int jn = 0; jn < 4; ++jn) {
      bf16x8 vf = *(const bf16x8*)&VT[(jn * 16 + l16) * 32 + quad * 8];
      O[mi][jn] = mfma_bf16(pf, vf, O[mi][jn]);
    }
  }
#pragma unroll
  for (int mi = 0; mi < 2; ++mi)
#pragma unroll
    for (int jn = 0; jn < 4; ++jn)
#pragma unroll
      for (int r = 0; r < 4; ++r) {
        int t = mi * 16 + quad * 4 + r;
        ao[TOK(t) * 768 + hh * 64 + jn * 16 + l16] = f2bs(O[mi][jn][r]);
      }
#undef TOK
}

// ---------------------------------------------------------------------------
extern "C" void kernel_launch(void* const* d_in, const int* in_sizes, int n_in,
                              void* d_out, int out_size, void* d_ws, size_t ws_size,
                              hipStream_t stream)
{
  const float* emb     = (const float*)d_in[0];
  const float* Wq_t    = (const float*)d_in[1];
  const float* Wk_t    = (const float*)d_in[2];
  const float* Wv_t    = (const float*)d_in[3];
  const float* Wo_t    = (const float*)d_in[4];
  const float* bo_t    = (const float*)d_in[5];
  const float* Wq_s    = (const float*)d_in[6];
  const float* Wk_s    = (const float*)d_in[7];
  const float* Wv_s    = (const float*)d_in[8];
  const float* Wo_s    = (const float*)d_in[9];
  const float* bo_s    = (const float*)d_in[10];
  const float* ln_t_sc = (const float*)d_in[11];
  const float* ln_t_bi = (const float*)d_in[12];
  const float* ln_s_sc = (const float*)d_in[13];
  const float* ln_s_bi = (const float*)d_in[14];
  const float* ln2_sc  = (const float*)d_in[15];
  const float* ln2_bi  = (const float*)d_in[16];
  const float* W1      = (const float*)d_in[17];
  const float* b1      = (const float*)d_in[18];
  const float* W2      = (const float*)d_in[19];
  const float* b2      = (const float*)d_in[20];

  const long M = 16384, D = 768, QN = 2304, F = 3072;
  char* ws = (char*)d_ws;
  size_t off = 0;
  auto alloc = [&](size_t b) { char* p = ws + off; off += (b + 255) & ~(size_t)255; return p; };
  short* qkvT_t = (short*)alloc((size_t)4 * QN * D * 2);   // 14.2 MB
  short* qkvT_s = (short*)alloc((size_t)4 * QN * D * 2);   // 14.2 MB
  short* woT_t  = (short*)alloc((size_t)4 * D * D * 2);    //  4.7 MB
  short* woT_s  = (short*)alloc((size_t)4 * D * D * 2);    //  4.7 MB
  short* w1T    = (short*)alloc((size_t)4 * F * D * 2);    // 18.9 MB
  short* w2T    = (short*)alloc((size_t)4 * D * F * 2);    // 18.9 MB
  short* xb     = (short*)alloc((size_t)M * D * 2);        // 25.2 MB
  short* aob    = (short*)alloc((size_t)M * D * 2);        // 25.2 MB
  short* big    = (short*)alloc((size_t)M * F * 2);        // 100.7 MB (qkv & ffn1)
  float* h = (float*)d_out;

  hipMemcpyAsync(h, emb, (size_t)M * D * 4, hipMemcpyDeviceToDevice, stream);

  // ---- weight prep: fp32 [K][N] -> bf16 [N][K], all 4 layers per launch ------
  transpose_w<<<dim3(24, 24, 4), 256, 0, stream>>>(Wq_t, qkvT_t,             768, 768,  D * D, QN * D);
  transpose_w<<<dim3(24, 24, 4), 256, 0, stream>>>(Wk_t, qkvT_t + D * D,     768, 768,  D * D, QN * D);
  transpose_w<<<dim3(24, 24, 4), 256, 0, stream>>>(Wv_t, qkvT_t + 2 * D * D, 768, 768,  D * D, QN * D);
  transpose_w<<<dim3(24, 24, 4), 256, 0, stream>>>(Wq_s, qkvT_s,             768, 768,  D * D, QN * D);
  transpose_w<<<dim3(24, 24, 4), 256, 0, stream>>>(Wk_s, qkvT_s + D * D,     768, 768,  D * D, QN * D);
  transpose_w<<<dim3(24, 24, 4), 256, 0, stream>>>(Wv_s, qkvT_s + 2 * D * D, 768, 768,  D * D, QN * D);
  transpose_w<<<dim3(24, 24, 4), 256, 0, stream>>>(Wo_t, woT_t,              768, 768,  D * D, D * D);
  transpose_w<<<dim3(24, 24, 4), 256, 0, stream>>>(Wo_s, woT_s,              768, 768,  D * D, D * D);
  transpose_w<<<dim3(96, 24, 4), 256, 0, stream>>>(W1,   w1T,                768, 3072, D * F, F * D);
  transpose_w<<<dim3(24, 96, 4), 256, 0, stream>>>(W2,   w2T,                3072, 768, F * D, D * F);

  // ---- layers ---------------------------------------------------------------
  for (int l = 0; l < 4; ++l) {
    // time attention block
    ln_kernel<<<16384, 256, 0, stream>>>(h, ln_t_sc + l * 768, ln_t_bi + l * 768, xb);
    gemm256<0><<<9 * 64, 512, 0, stream>>>(xb, qkvT_t + (long)l * QN * D,
        nullptr, nullptr, nullptr, big, 16384, 2304, 768, 9);
    attn_time<<<dim3(256, 12, 2), 64, 0, stream>>>(big, aob);
    gemm256<1><<<3 * 64, 512, 0, stream>>>(aob, woT_t + (long)l * D * D,
        bo_t + l * 768, h, h, nullptr, 16384, 768, 768, 3);
    // space attention block
    ln_kernel<<<16384, 256, 0, stream>>>(h, ln_s_sc + l * 768, ln_s_bi + l * 768, xb);
    gemm256<0><<<9 * 64, 512, 0, stream>>>(xb, qkvT_s + (long)l * QN * D,
        nullptr, nullptr, nullptr, big, 16384, 2304, 768, 9);
    attn_space<<<dim3(4, 12, 64), 256, 0, stream>>>(big, aob);
    gemm256<1><<<3 * 64, 512, 0, stream>>>(aob, woT_s + (long)l * D * D,
        bo_s + l * 768, h, h, nullptr, 16384, 768, 768, 3);
    // FFN block
    ln_kernel<<<16384, 256, 0, stream>>>(h, ln2_sc + l * 768, ln2_bi + l * 768, xb);
    gemm256<2><<<12 * 64, 512, 0, stream>>>(xb, w1T + (long)l * F * D,
        b1 + l * 3072, nullptr, nullptr, big, 16384, 3072, 768, 12);
    gemm256<1><<<3 * 64, 512, 0, stream>>>(big, w2T + (long)l * D * F,
        b2 + l * 768, h, h, nullptr, 16384, 768, 3072, 3);
  }
}